// Round 2
// baseline (627.946 us; speedup 1.0000x reference)
//
#include <hip/hip_runtime.h>
#include <hip/hip_bf16.h>

typedef __bf16 v8bf16 __attribute__((ext_vector_type(8)));
typedef __bf16 v2bf16 __attribute__((ext_vector_type(2)));
typedef float  v4f    __attribute__((ext_vector_type(4)));
typedef unsigned int u32;

#define SEQ     8192
#define DIM     64
#define OUTSEQ  7936
#define WIN     512
#define HALF    256
#define BH      32
#define NCHUNK  15          // full 512-wide chunks per bh
#define MAXT    17          // 1 global tile + 16 window tiles
#define NWG_CH  1920        // 480 chunks * 4 q-tiles (128 q each)
#define VROWT   40          // per-tile Vt row stride (bf16): 32 cols + swizzle pad

__device__ __forceinline__ v8bf16 cvt8(v4f a, v4f b) {
    v8bf16 r;
    r[0] = (__bf16)a[0]; r[1] = (__bf16)a[1];
    r[2] = (__bf16)a[2]; r[3] = (__bf16)a[3];
    r[4] = (__bf16)b[0]; r[5] = (__bf16)b[1];
    r[6] = (__bf16)b[2]; r[7] = (__bf16)b[3];
    return r;
}

__device__ __forceinline__ v8bf16 load8bf(const float* __restrict__ p) {
    const v4f a = *(const v4f*)p;
    const v4f b = *(const v4f*)(p + 4);
    return cvt8(a, b);
}

// pack two floats to bf16x2 in one dword
__device__ __forceinline__ u32 pk2(float lo, float hi) {
    v2bf16 p; p[0] = (__bf16)lo; p[1] = (__bf16)hi;
    return __builtin_bit_cast(u32, p);
}

// per-tile swizzled Vt index: col' = col ^ (8*((d>>3)&3))
// read (b128, 16 d-rows x 4 quads): uniform 8 accesses/bank (minimal for 1KB).
// write (v2bf16): 2-way aliasing only (free per m136).
__device__ __forceinline__ int vt_idx(int d, int col) {
    return d * VROWT + (col ^ (((d >> 3) & 3) << 3));
}

// launch_bounds (256,8): VGPR already landed at 64 with (256,4); 8 waves/EU
// permits 8 blocks/CU -> entire 1984-block grid co-resident (31 waves/CU).
__global__ __launch_bounds__(256, 8)
void swa_fwd(const float* __restrict__ qg,
             const float* __restrict__ kg,
             const float* __restrict__ vg,
             float* __restrict__ outg)
{
    // double-buffered single-tile V^T: 2 x 64 x 40 x 2B = 10240 B total LDS
    __shared__ __align__(16) __bf16 Vt[2][DIM * VROWT];

    // ---- XCD-aware mapping: the 4 q-tiles of one chunk share (id & 7) ----
    const int b = blockIdx.x;
    int bh, qoff, koff, ntiles;
    if (b < NWG_CH) {
        const int x  = b & 7;
        const int j  = b >> 3;        // 0..239
        const int qt = j & 3;
        const int cg = ((j >> 2) << 3) | x;   // chunk id 0..479
        bh = cg / NCHUNK;
        const int c = cg - bh * NCHUNK;
        koff = HALF + c * WIN;
        qoff = koff + qt * 128;
        ntiles = MAXT;
    } else {                          // first half-window block: 2 WGs x 128 q
        const int i = b - NWG_CH;     // 0..63
        bh = i >> 1;
        qoff = (i & 1) * 128;
        koff = 0;
        ntiles = 9;
    }

    const float* qb = qg + (size_t)bh * SEQ * DIM;
    const float* kb = kg + (size_t)bh * SEQ * DIM;
    const float* vb = vg + (size_t)bh * SEQ * DIM;

    const int tid  = threadIdx.x;
    const int wave = tid >> 6;
    const int lane = tid & 63;
    const int l15  = lane & 15;
    const int quad = lane >> 4;

    // ---- Q fragments as MFMA *B* operand: B[k=d][n=query], n=l15, k=quad*8+j
    // wave covers 32 queries: 2 subtiles of 16
    const int qbase = qoff + wave * 32;
    v8bf16 qf[2][2];
    #pragma unroll
    for (int qs = 0; qs < 2; ++qs) {
        const float* qp = qb + (size_t)(qbase + qs * 16 + l15) * DIM + quad * 8;
        qf[qs][0] = load8bf(qp);
        qf[qs][1] = load8bf(qp + 32);
    }

    // staging lane roles (whole WG stages one 32-key tile)
    const int keyduo = tid >> 4;      // tokens 2kd, 2kd+1
    const int dquad  = tid & 15;      // d = dquad*4 + i

    // ==== prologue: stage tile 0 (global tokens 0..31) into buffer 0 ====
    {
        const int tokA = 2 * keyduo;
        const v4f a  = *(const v4f*)(vb + (size_t)tokA * DIM + dquad * 4);
        const v4f b2 = *(const v4f*)(vb + (size_t)(tokA + 1) * DIM + dquad * 4);
        #pragma unroll
        for (int i = 0; i < 4; ++i) {
            v2bf16 pr; pr[0] = (__bf16)a[i]; pr[1] = (__bf16)b2[i];
            *(v2bf16*)(&Vt[0][vt_idx(dquad * 4 + i, 2 * keyduo)]) = pr;
        }
    }
    __syncthreads();

    // ==== main loop: S^T via MFMA(K,Q); exp in regs; shfl-transform to pf;
    //      O^T = V^T * P^T; stage next V tile double-buffered (T14 split) ====
    const float cexp = 0.125f * 1.44269504089f;   // scale * log2(e)
    const v4f vzero = {0.f, 0.f, 0.f, 0.f};
    float lsum[2] = {0.f, 0.f};
    v4f oacc[2][4];                    // [qs][dt], C: row=d(quad*4+rr), col=query(l15)
    #pragma unroll
    for (int qs = 0; qs < 2; ++qs)
        #pragma unroll
        for (int dt = 0; dt < 4; ++dt) oacc[qs][dt] = vzero;

    const int srcA = ((quad & 1) << 5) + l15;   // source lanes for pf permute
    const int srcB = srcA + 16;
    const bool hi  = quad >= 2;

    int cur = 0;
    for (int t = 0; t < ntiles; ++t) {
        const int base = (t == 0) ? 0 : koff + (t - 1) * 32;
        const bool have_next = (t + 1 < ntiles);

        // T14 issue-early: global loads for next V tile (consumed after PV)
        v4f sva, svb;
        if (have_next) {
            const int tokA = koff + t * 32 + 2 * keyduo;
            sva = *(const v4f*)(vb + (size_t)tokA * DIM + dquad * 4);
            svb = *(const v4f*)(vb + (size_t)(tokA + 1) * DIM + dquad * 4);
        }

        // K fragments as MFMA *A* operand: A[m=key][k=d], m=l15, k=quad*8+j
        const float* kp = kb + (size_t)(base + l15) * DIM + quad * 8;
        const v8bf16 k00 = load8bf(kp);                      // keys base..base+15
        const v8bf16 k01 = load8bf(kp + 32);
        const v8bf16 k10 = load8bf(kp + 16 * DIM);           // keys base+16..+31
        const v8bf16 k11 = load8bf(kp + 16 * DIM + 32);

        // Vt fragments (A operand of PV): A[m=d][k=key], shared across qs
        const __bf16* vcur = Vt[cur];
        v8bf16 vf[4];
        #pragma unroll
        for (int dt = 0; dt < 4; ++dt)
            vf[dt] = *(const v8bf16*)(&vcur[vt_idx(dt * 16 + l15, quad * 8)]);

        #pragma unroll
        for (int qs = 0; qs < 2; ++qs) {
            // S^T[key][query]: row=key=quad*4+rr, col=query=l15
            const v4f S0 = __builtin_amdgcn_mfma_f32_16x16x32_bf16(k01, qf[qs][1],
                           __builtin_amdgcn_mfma_f32_16x16x32_bf16(k00, qf[qs][0], vzero, 0,0,0), 0,0,0);
            const v4f S1 = __builtin_amdgcn_mfma_f32_16x16x32_bf16(k11, qf[qs][1],
                           __builtin_amdgcn_mfma_f32_16x16x32_bf16(k10, qf[qs][0], vzero, 0,0,0), 0,0,0);

            float e0[4], e1[4];
            #pragma unroll
            for (int rr = 0; rr < 4; ++rr) {
                e0[rr] = __builtin_exp2f(S0[rr] * cexp);
                e1[rr] = __builtin_exp2f(S1[rr] * cexp);
                lsum[qs] += e0[rr] + e1[rr];
            }
            const u32 A0 = pk2(e0[0], e0[1]), B0 = pk2(e0[2], e0[3]);
            const u32 A1 = pk2(e1[0], e1[1]), B1 = pk2(e1[2], e1[3]);

            // build P A/B-frag: pf dword i = keys (quad*8+2i, +2i+1) of query l15
            const u32 t0 = (u32)__shfl((int)A0, srcA, 64), u0 = (u32)__shfl((int)A1, srcA, 64);
            const u32 t1 = (u32)__shfl((int)B0, srcA, 64), u1 = (u32)__shfl((int)B1, srcA, 64);
            const u32 t2 = (u32)__shfl((int)A0, srcB, 64), u2 = (u32)__shfl((int)A1, srcB, 64);
            const u32 t3 = (u32)__shfl((int)B0, srcB, 64), u3 = (u32)__shfl((int)B1, srcB, 64);
            u32 pd[4];
            pd[0] = hi ? u0 : t0;  pd[1] = hi ? u1 : t1;
            pd[2] = hi ? u2 : t2;  pd[3] = hi ? u3 : t3;
            const v8bf16 pf = __builtin_bit_cast(v8bf16, *(const u32(*)[4])pd);

            // O^T += V^T * P^T : C[m=d][n=query]
            #pragma unroll
            for (int dt = 0; dt < 4; ++dt)
                oacc[qs][dt] = __builtin_amdgcn_mfma_f32_16x16x32_bf16(vf[dt], pf, oacc[qs][dt], 0,0,0);
        }

        // T14 write-late: stage next tile into the other buffer
        if (have_next) {
            __bf16* vnxt = Vt[cur ^ 1];
            #pragma unroll
            for (int i = 0; i < 4; ++i) {
                v2bf16 pr; pr[0] = (__bf16)sva[i]; pr[1] = (__bf16)svb[i];
                *(v2bf16*)(&vnxt[vt_idx(dquad * 4 + i, 2 * keyduo)]) = pr;
            }
        }
        __syncthreads();   // gates: next iter's reads of vnxt AND overwrites of vcur
        cur ^= 1;
    }

    // ==== epilogue: reduce l across quads (same l15 column), store coalesced ====
    #pragma unroll
    for (int qs = 0; qs < 2; ++qs) {
        float l = lsum[qs];
        l += __shfl_xor(l, 16, 64);
        l += __shfl_xor(l, 32, 64);
        const float inv = 1.0f / l;
        float* ob = outg + ((size_t)bh * OUTSEQ + qbase + qs * 16 + l15) * DIM;
        #pragma unroll
        for (int dt = 0; dt < 4; ++dt) {
            v4f rv = oacc[qs][dt];
            rv[0] *= inv; rv[1] *= inv; rv[2] *= inv; rv[3] *= inv;
            *(v4f*)(ob + dt * 16 + quad * 4) = rv;
        }
    }
}

extern "C" void kernel_launch(void* const* d_in, const int* in_sizes, int n_in,
                              void* d_out, int out_size, void* d_ws, size_t ws_size,
                              hipStream_t stream) {
    const float* q = (const float*)d_in[0];
    const float* k = (const float*)d_in[1];
    const float* v = (const float*)d_in[2];
    float* out = (float*)d_out;

    const int n_wg = NWG_CH + BH * 2;   // 1920 + 64 = 1984
    swa_fwd<<<dim3(n_wg), dim3(256), 0, stream>>>(q, k, v, out);
}

// Round 5
// 288.955 us; speedup vs baseline: 2.1732x; 2.1732x over previous
//
#include <hip/hip_runtime.h>
#include <hip/hip_bf16.h>

typedef __bf16 v8bf16 __attribute__((ext_vector_type(8)));
typedef __bf16 v2bf16 __attribute__((ext_vector_type(2)));
typedef float  v4f    __attribute__((ext_vector_type(4)));
typedef unsigned int u32;

#define SEQ     8192
#define DIM     64
#define OUTSEQ  7936
#define WIN     512
#define HALF    256
#define BH      32
#define NCHUNK  15          // full 512-wide chunks per bh
#define MAXT    17          // 1 global tile + 16 window tiles
#define NWG_CH  1920        // 480 chunks * 4 q-tiles (128 q each)
#define VROWT   40          // per-tile Vt row stride (bf16): 32 cols + swizzle pad

__device__ __forceinline__ v8bf16 cvt8(v4f a, v4f b) {
    v8bf16 r;
    r[0] = (__bf16)a[0]; r[1] = (__bf16)a[1];
    r[2] = (__bf16)a[2]; r[3] = (__bf16)a[3];
    r[4] = (__bf16)b[0]; r[5] = (__bf16)b[1];
    r[6] = (__bf16)b[2]; r[7] = (__bf16)b[3];
    return r;
}

__device__ __forceinline__ v8bf16 load8bf(const float* __restrict__ p) {
    const v4f a = *(const v4f*)p;
    const v4f b = *(const v4f*)(p + 4);
    return cvt8(a, b);
}

// pack two floats to bf16x2 in one dword
__device__ __forceinline__ u32 pk2(float lo, float hi) {
    v2bf16 p; p[0] = (__bf16)lo; p[1] = (__bf16)hi;
    return __builtin_bit_cast(u32, p);
}

// per-tile swizzled Vt index: col' = col ^ (8*((d>>3)&3))
// read (b128, 16 d-rows x 4 quads): uniform 8 accesses/bank-quad (floor).
// write (v2bf16): 2-way aliasing only (free per m136).
__device__ __forceinline__ int vt_idx(int d, int col) {
    return d * VROWT + (col ^ (((d >> 3) & 3) << 3));
}

// launch_bounds (256,4): (256,8) forces 32 arch VGPR + massive spills
// (R2: FETCH 104->824 MB, dur 505us). Unified-file usage ~128/wave
// (arch + acc) -> 4 waves/SIMD; occupancy lever is closed, hide latency.
__global__ __launch_bounds__(256, 4)
void swa_fwd(const float* __restrict__ qg,
             const float* __restrict__ kg,
             const float* __restrict__ vg,
             float* __restrict__ outg)
{
    // double-buffered single-tile V^T: 2 x 64 x 40 x 2B = 10240 B total LDS
    __shared__ __align__(16) __bf16 Vt[2][DIM * VROWT];

    // ---- XCD-aware mapping: the 4 q-tiles of one chunk share (id & 7) ----
    const int b = blockIdx.x;
    int bh, qoff, koff, ntiles;
    if (b < NWG_CH) {
        const int x  = b & 7;
        const int j  = b >> 3;        // 0..239
        const int qt = j & 3;
        const int cg = ((j >> 2) << 3) | x;   // chunk id 0..479
        bh = cg / NCHUNK;
        const int c = cg - bh * NCHUNK;
        koff = HALF + c * WIN;
        qoff = koff + qt * 128;
        ntiles = MAXT;
    } else {                          // first half-window block: 2 WGs x 128 q
        const int i = b - NWG_CH;     // 0..63
        bh = i >> 1;
        qoff = (i & 1) * 128;
        koff = 0;
        ntiles = 9;
    }

    const float* qb = qg + (size_t)bh * SEQ * DIM;
    const float* kb = kg + (size_t)bh * SEQ * DIM;
    const float* vb = vg + (size_t)bh * SEQ * DIM;

    const int tid  = threadIdx.x;
    const int wave = tid >> 6;
    const int lane = tid & 63;
    const int l15  = lane & 15;
    const int quad = lane >> 4;

    // ---- Q fragments as MFMA *B* operand: B[k=d][n=query], n=l15, k=quad*8+j
    // wave covers 32 queries: 2 subtiles of 16
    const int qbase = qoff + wave * 32;
    v8bf16 qf[2][2];
    #pragma unroll
    for (int qs = 0; qs < 2; ++qs) {
        const float* qp = qb + (size_t)(qbase + qs * 16 + l15) * DIM + quad * 8;
        qf[qs][0] = load8bf(qp);
        qf[qs][1] = load8bf(qp + 32);
    }

    // staging lane roles (whole WG stages one 32-key tile)
    const int keyduo = tid >> 4;      // V: tokens 2kd, 2kd+1
    const int dquad  = tid & 15;      // V: d = dquad*4 + i

    // ==== prologue: stage V tile 0 into buffer 0; K tile 0 raw into regs ====
    v4f kraw[8];                       // next-tile K fp32 (32 VGPRs), T14 style
    {
        const int tokA = 2 * keyduo;
        const v4f a  = *(const v4f*)(vb + (size_t)tokA * DIM + dquad * 4);
        const v4f b2 = *(const v4f*)(vb + (size_t)(tokA + 1) * DIM + dquad * 4);
        #pragma unroll
        for (int i = 0; i < 4; ++i) {
            v2bf16 pr; pr[0] = (__bf16)a[i]; pr[1] = (__bf16)b2[i];
            *(v2bf16*)(&Vt[0][vt_idx(dquad * 4 + i, 2 * keyduo)]) = pr;
        }
        const float* kp = kb + (size_t)l15 * DIM + quad * 8;   // tile 0: rows 0..31
        kraw[0] = *(const v4f*)kp;                 kraw[1] = *(const v4f*)(kp + 4);
        kraw[2] = *(const v4f*)(kp + 32);          kraw[3] = *(const v4f*)(kp + 36);
        kraw[4] = *(const v4f*)(kp + 16 * DIM);    kraw[5] = *(const v4f*)(kp + 16 * DIM + 4);
        kraw[6] = *(const v4f*)(kp + 16 * DIM + 32); kraw[7] = *(const v4f*)(kp + 16 * DIM + 36);
    }
    __syncthreads();

    // ==== main loop: S^T via MFMA(K,Q); exp in regs; shfl-transform to pf;
    //      O^T = V^T * P^T; K+V of tile t+1 prefetched during tile t ====
    const float cexp = 0.125f * 1.44269504089f;   // scale * log2(e)
    const v4f vzero = {0.f, 0.f, 0.f, 0.f};
    float lsum[2] = {0.f, 0.f};
    v4f oacc[2][4];                    // [qs][dt], C: row=d(quad*4+rr), col=query(l15)
    #pragma unroll
    for (int qs = 0; qs < 2; ++qs)
        #pragma unroll
        for (int dt = 0; dt < 4; ++dt) oacc[qs][dt] = vzero;

    const int srcA = ((quad & 1) << 5) + l15;   // source lanes for pf permute
    const int srcB = srcA + 16;
    const bool hi  = quad >= 2;

    int cur = 0;
    for (int t = 0; t < ntiles; ++t) {
        const bool have_next = (t + 1 < ntiles);

        // K fragments for THIS tile: convert prefetched raw regs (data long
        // since arrived -> no waitcnt stall). A[m=key][k=d], m=l15, k=quad*8+j
        const v8bf16 k00 = cvt8(kraw[0], kraw[1]);
        const v8bf16 k01 = cvt8(kraw[2], kraw[3]);
        const v8bf16 k10 = cvt8(kraw[4], kraw[5]);
        const v8bf16 k11 = cvt8(kraw[6], kraw[7]);

        // T14 issue-early: global loads for NEXT K+V tiles (consumed after PV)
        v4f sva, svb;
        if (have_next) {
            const int nb = koff + t * 32;          // base of tile t+1
            const int tokA = nb + 2 * keyduo;
            sva = *(const v4f*)(vb + (size_t)tokA * DIM + dquad * 4);
            svb = *(const v4f*)(vb + (size_t)(tokA + 1) * DIM + dquad * 4);
            const float* kp = kb + (size_t)(nb + l15) * DIM + quad * 8;
            kraw[0] = *(const v4f*)kp;                 kraw[1] = *(const v4f*)(kp + 4);
            kraw[2] = *(const v4f*)(kp + 32);          kraw[3] = *(const v4f*)(kp + 36);
            kraw[4] = *(const v4f*)(kp + 16 * DIM);    kraw[5] = *(const v4f*)(kp + 16 * DIM + 4);
            kraw[6] = *(const v4f*)(kp + 16 * DIM + 32); kraw[7] = *(const v4f*)(kp + 16 * DIM + 36);
        }

        // Vt fragments (A operand of PV): A[m=d][k=key], shared across qs
        const __bf16* vcur = Vt[cur];
        v8bf16 vf[4];
        #pragma unroll
        for (int dt = 0; dt < 4; ++dt)
            vf[dt] = *(const v8bf16*)(&vcur[vt_idx(dt * 16 + l15, quad * 8)]);

        #pragma unroll
        for (int qs = 0; qs < 2; ++qs) {
            // S^T[key][query]: row=key=quad*4+rr, col=query=l15
            const v4f S0 = __builtin_amdgcn_mfma_f32_16x16x32_bf16(k01, qf[qs][1],
                           __builtin_amdgcn_mfma_f32_16x16x32_bf16(k00, qf[qs][0], vzero, 0,0,0), 0,0,0);
            const v4f S1 = __builtin_amdgcn_mfma_f32_16x16x32_bf16(k11, qf[qs][1],
                           __builtin_amdgcn_mfma_f32_16x16x32_bf16(k10, qf[qs][0], vzero, 0,0,0), 0,0,0);

            float e0[4], e1[4];
            #pragma unroll
            for (int rr = 0; rr < 4; ++rr) {
                e0[rr] = __builtin_exp2f(S0[rr] * cexp);
                e1[rr] = __builtin_exp2f(S1[rr] * cexp);
                lsum[qs] += e0[rr] + e1[rr];
            }
            const u32 A0 = pk2(e0[0], e0[1]), B0 = pk2(e0[2], e0[3]);
            const u32 A1 = pk2(e1[0], e1[1]), B1 = pk2(e1[2], e1[3]);

            // build P A/B-frag: pf dword i = keys (quad*8+2i, +2i+1) of query l15
            const u32 t0 = (u32)__shfl((int)A0, srcA, 64), u0 = (u32)__shfl((int)A1, srcA, 64);
            const u32 t1 = (u32)__shfl((int)B0, srcA, 64), u1 = (u32)__shfl((int)B1, srcA, 64);
            const u32 t2 = (u32)__shfl((int)A0, srcB, 64), u2 = (u32)__shfl((int)A1, srcB, 64);
            const u32 t3 = (u32)__shfl((int)B0, srcB, 64), u3 = (u32)__shfl((int)B1, srcB, 64);
            u32 pd[4];
            pd[0] = hi ? u0 : t0;  pd[1] = hi ? u1 : t1;
            pd[2] = hi ? u2 : t2;  pd[3] = hi ? u3 : t3;
            const v8bf16 pf = __builtin_bit_cast(v8bf16, *(const u32(*)[4])pd);

            // O^T += V^T * P^T : C[m=d][n=query]
            #pragma unroll
            for (int dt = 0; dt < 4; ++dt)
                oacc[qs][dt] = __builtin_amdgcn_mfma_f32_16x16x32_bf16(vf[dt], pf, oacc[qs][dt], 0,0,0);
        }

        // T14 write-late: stage next V tile into the other buffer
        if (have_next) {
            __bf16* vnxt = Vt[cur ^ 1];
            #pragma unroll
            for (int i = 0; i < 4; ++i) {
                v2bf16 pr; pr[0] = (__bf16)sva[i]; pr[1] = (__bf16)svb[i];
                *(v2bf16*)(&vnxt[vt_idx(dquad * 4 + i, 2 * keyduo)]) = pr;
            }
        }
        __syncthreads();   // gates: next iter's reads of vnxt AND overwrites of vcur
        cur ^= 1;
    }

    // ==== epilogue: reduce l across quads (same l15 column), store coalesced ====
    #pragma unroll
    for (int qs = 0; qs < 2; ++qs) {
        float l = lsum[qs];
        l += __shfl_xor(l, 16, 64);
        l += __shfl_xor(l, 32, 64);
        const float inv = 1.0f / l;
        float* ob = outg + ((size_t)bh * OUTSEQ + qbase + qs * 16 + l15) * DIM;
        #pragma unroll
        for (int dt = 0; dt < 4; ++dt) {
            v4f rv = oacc[qs][dt];
            rv[0] *= inv; rv[1] *= inv; rv[2] *= inv; rv[3] *= inv;
            *(v4f*)(ob + dt * 16 + quad * 4) = rv;
        }
    }
}

extern "C" void kernel_launch(void* const* d_in, const int* in_sizes, int n_in,
                              void* d_out, int out_size, void* d_ws, size_t ws_size,
                              hipStream_t stream) {
    const float* q = (const float*)d_in[0];
    const float* k = (const float*)d_in[1];
    const float* v = (const float*)d_in[2];
    float* out = (float*)d_out;

    const int n_wg = NWG_CH + BH * 2;   // 1920 + 64 = 1984
    swa_fwd<<<dim3(n_wg), dim3(256), 0, stream>>>(q, k, v, out);
}